// Round 1
// baseline (240.609 us; speedup 1.0000x reference)
//
#include <hip/hip_runtime.h>

// Problem constants (match reference)
#define DVOL 256
#define NVOX (DVOL * DVOL * DVOL)   // 16,777,216 voxels
#define N_LABELS 1000

// Fused kernel:
//   - Stage a fused (scale, mask) LUT into LDS once per block:
//       l == 0            -> scale 1.0, mask 0
//       keep_mask[l] == 0 -> scale 1.0, mask 0   (pruned to background)
//       else              -> scale intensity_lut[l], mask 1
//   - Grid-stride over voxels in float4/int4 groups (16B/lane coalesced).
//   - Outputs written as float32: out[0..NVOX) = parenchyma * scale,
//     out[NVOX..2*NVOX) = mask (harness reads the whole d_out as float32
//     and compares chunk-wise against the reference tuple).
__global__ __launch_bounds__(256)
void vessel_fuse_kernel(const int* __restrict__ labels,
                        const int* __restrict__ keep_mask,
                        const float* __restrict__ intensity_lut,
                        const float* __restrict__ parenchyma,
                        float* __restrict__ out,      // [NVOX] float32
                        float* __restrict__ maskf)    // [NVOX] float32 (0.0/1.0)
{
    __shared__ float s_scale[N_LABELS];
    __shared__ float s_mask[N_LABELS];

    for (int l = threadIdx.x; l < N_LABELS; l += 256) {
        const bool keep = (l > 0) && (keep_mask[l] > 0);
        s_scale[l] = keep ? intensity_lut[l] : 1.0f;
        s_mask[l]  = keep ? 1.0f : 0.0f;
    }
    __syncthreads();

    const int4*   lab4 = (const int4*)labels;
    const float4* par4 = (const float4*)parenchyma;
    float4* out4 = (float4*)out;
    float4* msk4 = (float4*)maskf;

    const int n4 = NVOX / 4;
    const int stride = gridDim.x * blockDim.x;
    for (int i = blockIdx.x * blockDim.x + threadIdx.x; i < n4; i += stride) {
        const int4   L = lab4[i];
        const float4 p = par4[i];
        float4 o, m;
        o.x = p.x * s_scale[L.x];  m.x = s_mask[L.x];
        o.y = p.y * s_scale[L.y];  m.y = s_mask[L.y];
        o.z = p.z * s_scale[L.z];  m.z = s_mask[L.z];
        o.w = p.w * s_scale[L.w];  m.w = s_mask[L.w];
        out4[i] = o;
        msk4[i] = m;
    }
}

extern "C" void kernel_launch(void* const* d_in, const int* in_sizes, int n_in,
                              void* d_out, int out_size, void* d_ws, size_t ws_size,
                              hipStream_t stream) {
    (void)in_sizes; (void)n_in; (void)d_ws; (void)ws_size; (void)out_size;

    const int*   vessel_labels = (const int*)d_in[0];   // [D,D,D] int32
    const int*   keep_mask     = (const int*)d_in[1];   // [N_LABELS] int32
    const float* intensity_lut = (const float*)d_in[2]; // [N_LABELS] float32
    const float* parenchyma    = (const float*)d_in[3]; // [D,D,D] float32

    float* out   = (float*)d_out;          // output 0: modulated parenchyma
    float* maskf = (float*)d_out + NVOX;   // output 1: vessel mask as float

    // 2048 blocks x 256 threads = 8 blocks/CU worth of waves; each thread
    // handles 8 float4 groups via grid-stride.
    const int blocks = 2048;
    vessel_fuse_kernel<<<blocks, 256, 0, stream>>>(
        vessel_labels, keep_mask, intensity_lut, parenchyma, out, maskf);
}